// Round 10
// baseline (116.426 us; speedup 1.0000x reference)
//
#include <hip/hip_runtime.h>
#include <hip/hip_bf16.h>

#define B_ 2
#define L_ 2048
#define H_ 8
#define D_ 64
#define SP_ 65       // STRIDE+1
#define NC_ 128      // level-1 chunks (16 rows each)
#define NL2_ 8       // level-2 chunks (256 rows each)
#define RS_ 512      // H_*D_ floats between consecutive seq rows

typedef __attribute__((ext_vector_type(8))) short bf16x8;
typedef __attribute__((ext_vector_type(16))) float f32x16;

static __device__ inline short f2bf(float x) {
    return __builtin_bit_cast(short, __float2bfloat16(x));
}

static __device__ inline bf16x8 ld8_bf16(const float* __restrict__ p) {
    float4 a = *(const float4*)p;
    float4 b = *(const float4*)(p + 4);
    bf16x8 r;
    r[0]=f2bf(a.x); r[1]=f2bf(a.y); r[2]=f2bf(a.z); r[3]=f2bf(a.w);
    r[4]=f2bf(b.x); r[5]=f2bf(b.y); r[6]=f2bf(b.z); r[7]=f2bf(b.w);
    return r;
}

static __device__ inline bf16x8 ones_frag() {
    bf16x8 r;
    short o = f2bf(1.f);
    #pragma unroll
    for (int t = 0; t < 8; ++t) r[t] = o;
    return r;
}

// ================= Kernel 1: ALL input-only partials in one launch ==========
// unit = blockIdx.x*4 + wave:
//   [0,1024)    local 32-row tile  -> pA, zA
//   [1024,2064) strided residue    -> pB, zB
//   [2064,4112) csum1 (16-row sums of V)
//   [4112,4240) csum2 (256-row sums of V, direct)
__global__ __launch_bounds__(256) void partials_k(const float* __restrict__ q,
                                                  const float* __restrict__ kk,
                                                  const float* __restrict__ v,
                                                  float* __restrict__ csum1,
                                                  float* __restrict__ csum2,
                                                  float* __restrict__ pA,
                                                  float* __restrict__ zA,
                                                  float* __restrict__ pB,
                                                  float* __restrict__ zB) {
    __shared__ float Pw[4][32][68];
    int wib  = threadIdx.x >> 6;
    int lane = threadIdx.x & 63;
    int half = lane >> 5, ln = lane & 31;
    int u = blockIdx.x * 4 + wib;

    if (u < 1024) {
        // ---------- local tile: 32 query rows, key band [T-16, T+48)
        int bh = u >> 6;
        int T  = (u & 63) << 5;
        int h = bh & 7, b = bh >> 3;
        const size_t base = (size_t)b * L_ * RS_ + (size_t)h * D_;

        // V band prefetch first (deep independent loads)
        bf16x8 bv0[4], bv1[4];
        #pragma unroll
        for (int kb = 0; kb < 4; ++kb) {
            int k0 = kb * 16 + half * 8;
            #pragma unroll
            for (int jj = 0; jj < 8; ++jj) {
                int jr = T - 16 + k0 + jj;
                jr = jr < 0 ? 0 : (jr > L_ - 1 ? L_ - 1 : jr);
                const float* vr = v + base + (size_t)jr * RS_;
                bv0[kb][jj] = f2bf(vr[ln]);
                bv1[kb][jj] = f2bf(vr[32 + ln]);
            }
        }

        const float* qrow = q + base + (size_t)(T + ln) * RS_;
        bf16x8 aq[4];
        #pragma unroll
        for (int kb = 0; kb < 4; ++kb) aq[kb] = ld8_bf16(qrow + kb * 16 + half * 8);

        int j0 = T - 16 + ln; j0 = j0 < 0 ? 0 : j0;
        int j1 = T + 16 + ln; j1 = j1 > L_ - 1 ? L_ - 1 : j1;
        const float* kr0 = kk + base + (size_t)j0 * RS_;
        const float* kr1 = kk + base + (size_t)j1 * RS_;
        f32x16 acc0 = {}; f32x16 acc1 = {};
        #pragma unroll
        for (int kb = 0; kb < 4; ++kb) {
            bf16x8 b0 = ld8_bf16(kr0 + kb * 16 + half * 8);
            bf16x8 b1 = ld8_bf16(kr1 + kb * 16 + half * 8);
            acc0 = __builtin_amdgcn_mfma_f32_32x32x16_bf16(aq[kb], b0, acc0, 0, 0, 0);
            acc1 = __builtin_amdgcn_mfma_f32_32x32x16_bf16(aq[kb], b1, acc1, 0, 0, 0);
        }

        // weights (exp-1 masked + "+1" prefix-fold for partial chunk rows)
        #pragma unroll
        for (int r = 0; r < 16; ++r) {
            int m = (r & 3) + 8 * (r >> 2) + 4 * half;
            bool a0 = (ln >= m) && (ln <= m + 16) && (T - 16 + ln >= 0);
            float w0 = a0 ? (__expf(0.125f * acc0[r]) - 1.f) : 0.f;
            if ((m < 16) && (ln >= 16) && (ln <= m + 16)) w0 += 1.f;
            bool a1 = (ln <= m - 16);
            float w1 = a1 ? (__expf(0.125f * acc1[r]) - 1.f) : 0.f;
            if ((m >= 16) && (ln <= m - 16)) w1 += 1.f;
            Pw[wib][m][ln]      = w0;
            Pw[wib][m][32 + ln] = w1;
        }
        __syncthreads();

        f32x16 p0 = {}; f32x16 p1 = {}; f32x16 po = {};
        bf16x8 ones = ones_frag();
        #pragma unroll
        for (int kb = 0; kb < 4; ++kb) {
            int k0 = kb * 16 + half * 8;
            const float* pr = &Pw[wib][ln][k0];
            float4 x = *(const float4*)pr;
            float4 y = *(const float4*)(pr + 4);
            bf16x8 ap;
            ap[0]=f2bf(x.x); ap[1]=f2bf(x.y); ap[2]=f2bf(x.z); ap[3]=f2bf(x.w);
            ap[4]=f2bf(y.x); ap[5]=f2bf(y.y); ap[6]=f2bf(y.z); ap[7]=f2bf(y.w);
            p0 = __builtin_amdgcn_mfma_f32_32x32x16_bf16(ap, bv0[kb], p0, 0, 0, 0);
            p1 = __builtin_amdgcn_mfma_f32_32x32x16_bf16(ap, bv1[kb], p1, 0, 0, 0);
            po = __builtin_amdgcn_mfma_f32_32x32x16_bf16(ap, ones,    po, 0, 0, 0);
        }

        float* pAr = pA + (size_t)bh * L_ * D_;
        float* zAr = zA + (size_t)bh * L_;
        #pragma unroll
        for (int r = 0; r < 16; ++r) {
            int m = (r & 3) + 8 * (r >> 2) + 4 * half;
            int i = T + m;
            pAr[(size_t)i * D_ + ln]      = p0[r];
            pAr[(size_t)i * D_ + 32 + ln] = p1[r];
            if (ln == 0) zAr[i] = po[r] - (float)((m & 15) + 1);
        }
    } else if (u < 2064) {
        // ---------- strided residue class mod 65: rows l = r + 65*s, s=0..31
        int us = u - 1024;               // 0..1039
        int bh = us / SP_;
        int r  = us % SP_;
        int h = bh & 7, b = bh >> 3;
        const size_t base = (size_t)b * L_ * RS_ + (size_t)h * D_;

        bf16x8 bv0[2], bv1[2];
        #pragma unroll
        for (int kb = 0; kb < 2; ++kb) {
            int k0 = kb * 16 + half * 8;
            #pragma unroll
            for (int jj = 0; jj < 8; ++jj) {
                int lv = r + SP_ * (k0 + jj);
                lv = lv > L_ - 1 ? L_ - 1 : lv;
                const float* vr = v + base + (size_t)lv * RS_;
                bv0[kb][jj] = f2bf(vr[ln]);
                bv1[kb][jj] = f2bf(vr[32 + ln]);
            }
        }

        int lq = r + SP_ * ln;
        int lqc = lq > L_ - 1 ? L_ - 1 : lq;
        const float* qrow = q  + base + (size_t)lqc * RS_;
        const float* krow = kk + base + (size_t)lqc * RS_;
        f32x16 acc = {};
        #pragma unroll
        for (int kb = 0; kb < 4; ++kb) {
            bf16x8 a  = ld8_bf16(qrow + kb * 16 + half * 8);
            bf16x8 bb = ld8_bf16(krow + kb * 16 + half * 8);
            acc = __builtin_amdgcn_mfma_f32_32x32x16_bf16(a, bb, acc, 0, 0, 0);
        }
        #pragma unroll
        for (int rg = 0; rg < 16; ++rg) {
            int m = (rg & 3) + 8 * (rg >> 2) + 4 * half;
            bool act = (ln < m) && (r + SP_ * m < L_);
            Pw[wib][m][ln] = act ? (__expf(0.125f * acc[rg]) - 1.f) : 0.f;
        }
        __syncthreads();

        f32x16 p0 = {}; f32x16 p1 = {}; f32x16 po = {};
        bf16x8 ones = ones_frag();
        #pragma unroll
        for (int kb = 0; kb < 2; ++kb) {
            int k0 = kb * 16 + half * 8;
            const float* pr = &Pw[wib][ln][k0];
            float4 x = *(const float4*)pr;
            float4 y = *(const float4*)(pr + 4);
            bf16x8 ap;
            ap[0]=f2bf(x.x); ap[1]=f2bf(x.y); ap[2]=f2bf(x.z); ap[3]=f2bf(x.w);
            ap[4]=f2bf(y.x); ap[5]=f2bf(y.y); ap[6]=f2bf(y.z); ap[7]=f2bf(y.w);
            p0 = __builtin_amdgcn_mfma_f32_32x32x16_bf16(ap, bv0[kb], p0, 0, 0, 0);
            p1 = __builtin_amdgcn_mfma_f32_32x32x16_bf16(ap, bv1[kb], p1, 0, 0, 0);
            po = __builtin_amdgcn_mfma_f32_32x32x16_bf16(ap, ones,    po, 0, 0, 0);
        }
        float* pBr = pB + (size_t)bh * L_ * D_;
        float* zBr = zB + (size_t)bh * L_;
        #pragma unroll
        for (int rg = 0; rg < 16; ++rg) {
            int m = (rg & 3) + 8 * (rg >> 2) + 4 * half;
            int l = r + SP_ * m;
            if (l < L_) {
                pBr[(size_t)l * D_ + ln]      = p0[rg];
                pBr[(size_t)l * D_ + 32 + ln] = p1[rg];
                if (ln == 0) zBr[l] = po[rg];
            }
        }
    } else if (u < 4112) {
        // ---------- csum1: 16-row chunk sums
        int uc = u - 2064;               // 0..2047 = bh*128 + c
        int c = uc & (NC_ - 1);
        int bh = uc >> 7;
        int h = bh & 7, b = bh >> 3;
        const float* vb = v + (size_t)(b * L_ + c * 16) * RS_ + h * D_ + lane;
        float s = 0.f;
        #pragma unroll
        for (int l = 0; l < 16; ++l) s += vb[l * RS_];
        csum1[(size_t)uc * D_ + lane] = s;
    } else {
        // ---------- csum2 direct from V: 256-row sums
        int uc = u - 4112;               // 0..127 = bh*8 + c2
        int c2 = uc & 7;
        int bh = uc >> 3;
        int h = bh & 7, b = bh >> 3;
        const float* vb = v + (size_t)(b * L_ + c2 * 256) * RS_ + h * D_ + lane;
        float s0 = 0.f, s1 = 0.f, s2 = 0.f, s3 = 0.f;
        for (int l = 0; l < 256; l += 4) {
            s0 += vb[(l + 0) * RS_]; s1 += vb[(l + 1) * RS_];
            s2 += vb[(l + 2) * RS_]; s3 += vb[(l + 3) * RS_];
        }
        csum2[(size_t)uc * D_ + lane] = (s0 + s1) + (s2 + s3);
    }
}

// ================= Kernel 2: combine + prefix + divide (streaming) ==========
// One wave per 16-row group (2048 waves, 512 blocks). Lane = dim.
__global__ __launch_bounds__(256) void combine_k(const float* __restrict__ csum1,
                                                 const float* __restrict__ csum2,
                                                 const float* __restrict__ pA,
                                                 const float* __restrict__ zA,
                                                 const float* __restrict__ pB,
                                                 const float* __restrict__ zB,
                                                 float* __restrict__ out) {
    int wib  = threadIdx.x >> 6;
    int lane = threadIdx.x & 63;
    int u = blockIdx.x * 4 + wib;        // 0..2047
    int bh = u >> 7;
    int g  = u & 127;                    // level-1 chunk index = i>>4
    int i0 = g << 4;
    int h = bh & 7, b = bh >> 3;

    // prefix walk: full level-2 chunks below, then level-1 chunks within
    int c2 = i0 >> 8;
    const float* cs2 = csum2 + (size_t)bh * NL2_ * D_;
    const float* cs1 = csum1 + (size_t)bh * NC_ * D_;
    float pr = 0.f;
    for (int cc = 0; cc < c2; ++cc)        pr += cs2[cc * D_ + lane];
    for (int cc = c2 << 4; cc < g; ++cc)   pr += cs1[cc * D_ + lane];

    const float* pAr = pA + (size_t)bh * L_ * D_;
    const float* pBr = pB + (size_t)bh * L_ * D_;
    const float* zAr = zA + (size_t)bh * L_;
    const float* zBr = zB + (size_t)bh * L_;
    const size_t obase = (size_t)b * L_ * RS_ + (size_t)h * D_;

    #pragma unroll
    for (int r = 0; r < 16; ++r) {
        int i = i0 + r;
        float num = pAr[(size_t)i * D_ + lane] + pBr[(size_t)i * D_ + lane] + pr;
        float inv = 1.f / (zAr[i] + zBr[i] + (float)(i + 1));
        out[obase + (size_t)i * RS_ + lane] = num * inv;
    }
}

extern "C" void kernel_launch(void* const* d_in, const int* in_sizes, int n_in,
                              void* d_out, int out_size, void* d_ws, size_t ws_size,
                              hipStream_t stream) {
    const float* q = (const float*)d_in[0];
    const float* k = (const float*)d_in[1];
    const float* v = (const float*)d_in[2];
    // d_in[3] = attn_mask: deterministic causal — not read.
    float* out = (float*)d_out;

    float* csum1 = (float*)d_ws;                          // 131072 f
    float* csum2 = csum1 + (size_t)B_ * H_ * NC_ * D_;    // 8192 f
    float* pA    = csum2 + (size_t)B_ * H_ * NL2_ * D_;   // 2097152 f
    float* zA    = pA    + (size_t)B_ * H_ * L_ * D_;     // 32768 f
    float* pB    = zA    + (size_t)B_ * H_ * L_;          // 2097152 f
    float* zB    = pB    + (size_t)B_ * H_ * L_ * D_;     // 32768 f

    // 1024 local + 1040 strided + 2048 csum1 + 128 csum2 = 4240 units
    partials_k<<<1060, 256, 0, stream>>>(q, k, v, csum1, csum2, pA, zA, pB, zB);
    // combine: 2048 16-row groups, 4 waves/block
    combine_k<<<512, 256, 0, stream>>>(csum1, csum2, pA, zA, pB, zB, out);
}

// Round 11
// 112.009 us; speedup vs baseline: 1.0394x; 1.0394x over previous
//
#include <hip/hip_runtime.h>
#include <hip/hip_bf16.h>

#define B_ 2
#define L_ 2048
#define H_ 8
#define D_ 64
#define SP_ 65       // STRIDE+1
#define NC_ 128      // level-1 chunks (16 rows each)
#define RS_ 512      // H_*D_ floats between consecutive seq rows

typedef __attribute__((ext_vector_type(8))) short bf16x8;
typedef __attribute__((ext_vector_type(16))) float f32x16;

static __device__ inline short f2bf(float x) {
    return __builtin_bit_cast(short, __float2bfloat16(x));
}

static __device__ inline bf16x8 ld8_bf16(const float* __restrict__ p) {
    float4 a = *(const float4*)p;
    float4 b = *(const float4*)(p + 4);
    bf16x8 r;
    r[0]=f2bf(a.x); r[1]=f2bf(a.y); r[2]=f2bf(a.z); r[3]=f2bf(a.w);
    r[4]=f2bf(b.x); r[5]=f2bf(b.y); r[6]=f2bf(b.z); r[7]=f2bf(b.w);
    return r;
}

static __device__ inline bf16x8 ones_frag() {
    bf16x8 r;
    short o = f2bf(1.f);
    #pragma unroll
    for (int t = 0; t < 8; ++t) r[t] = o;
    return r;
}

// ================= Kernel 1: ALL input-only partials, one launch ============
// blk <  512 : local 32-row tiles, 2-wave teams (2 teams/block; 1024 tiles)
// blk <  772 : strided residue units (4 waves/block, 1040 units)
// blk < 1284 : csum1 16-row V sums (4 waves/block, 2048 units)
__global__ __launch_bounds__(256) void partials_k(const float* __restrict__ q,
                                                  const float* __restrict__ kk,
                                                  const float* __restrict__ v,
                                                  float* __restrict__ csum1,
                                                  float* __restrict__ pA,
                                                  float* __restrict__ zA,
                                                  float* __restrict__ pB,
                                                  float* __restrict__ zB) {
    __shared__ float LDS[4608];          // local: 2 teams x 32x68; strided: 4 x 32x36
    int wib  = threadIdx.x >> 6;
    int lane = threadIdx.x & 63;
    int half = lane >> 5, ln = lane & 31;
    int blk  = blockIdx.x;

    if (blk < 512) {
        // ---------- local tile, 2-wave team: this wave = col-tile hf, dims [32*hf,32*hf+32)
        int tb = wib >> 1;               // team in block
        int hf = wib & 1;                // 0: cols [T-16,T+16); 1: cols [T+16,T+48)
        int team = blk * 2 + tb;         // 0..1023
        int bh = team >> 6;
        int T  = (team & 63) << 5;
        int h = bh & 7, b = bh >> 3;
        const size_t base = (size_t)b * L_ * RS_ + (size_t)h * D_;
        float* Pw = LDS + tb * 2176;     // [32][68]
        int d0 = 32 * hf;

        // V prefetch: band rows for this wave's kb/half, dims [d0, d0+32)
        bf16x8 bv[4];
        #pragma unroll
        for (int kb = 0; kb < 4; ++kb) {
            #pragma unroll
            for (int jj = 0; jj < 8; ++jj) {
                int jr = T - 16 + kb * 16 + half * 8 + jj;
                jr = jr < 0 ? 0 : (jr > L_ - 1 ? L_ - 1 : jr);
                bv[kb][jj] = f2bf(v[base + (size_t)jr * RS_ + d0 + ln]);
            }
        }

        // QK^T for this wave's 32-col tile
        const float* qrow = q + base + (size_t)(T + ln) * RS_;
        bf16x8 aq[4];
        #pragma unroll
        for (int kb = 0; kb < 4; ++kb) aq[kb] = ld8_bf16(qrow + kb * 16 + half * 8);

        int j = T - 16 + 32 * hf + ln;
        j = j < 0 ? 0 : (j > L_ - 1 ? L_ - 1 : j);
        const float* krow = kk + base + (size_t)j * RS_;
        f32x16 acc = {};
        #pragma unroll
        for (int kb = 0; kb < 4; ++kb) {
            bf16x8 kf = ld8_bf16(krow + kb * 16 + half * 8);
            acc = __builtin_amdgcn_mfma_f32_32x32x16_bf16(aq[kb], kf, acc, 0, 0, 0);
        }

        // weights (exp-1 masked + "+1" prefix fold) into this wave's col half
        #pragma unroll
        for (int r = 0; r < 16; ++r) {
            int m = (r & 3) + 8 * (r >> 2) + 4 * half;
            float w;
            if (hf == 0) {
                bool act = (ln >= m) && (ln <= m + 16) && (T - 16 + ln >= 0);
                w = act ? (__expf(0.125f * acc[r]) - 1.f) : 0.f;
                if ((m < 16) && (ln >= 16) && (ln <= m + 16)) w += 1.f;
            } else {
                bool act = (ln <= m - 16);
                w = act ? (__expf(0.125f * acc[r]) - 1.f) : 0.f;
                if ((m >= 16) && (ln <= m - 16)) w += 1.f;
            }
            Pw[m * 68 + d0 + ln] = w;
        }
        __syncthreads();

        // PV over full 64-col band, this wave's 32 output dims (+ po on hf==0)
        f32x16 p = {}; f32x16 po = {};
        bf16x8 ones = ones_frag();
        #pragma unroll
        for (int kb = 0; kb < 4; ++kb) {
            int k0 = kb * 16 + half * 8;
            const float* pr = &Pw[ln * 68 + k0];
            float4 x = *(const float4*)pr;
            float4 y = *(const float4*)(pr + 4);
            bf16x8 ap;
            ap[0]=f2bf(x.x); ap[1]=f2bf(x.y); ap[2]=f2bf(x.z); ap[3]=f2bf(x.w);
            ap[4]=f2bf(y.x); ap[5]=f2bf(y.y); ap[6]=f2bf(y.z); ap[7]=f2bf(y.w);
            p = __builtin_amdgcn_mfma_f32_32x32x16_bf16(ap, bv[kb], p, 0, 0, 0);
            if (hf == 0)
                po = __builtin_amdgcn_mfma_f32_32x32x16_bf16(ap, ones, po, 0, 0, 0);
        }

        float* pAr = pA + (size_t)bh * L_ * D_;
        float* zAr = zA + (size_t)bh * L_;
        #pragma unroll
        for (int r = 0; r < 16; ++r) {
            int m = (r & 3) + 8 * (r >> 2) + 4 * half;
            int i = T + m;
            pAr[(size_t)i * D_ + d0 + ln] = p[r];
            if (hf == 0 && ln == 0)
                zAr[i] = po[r] - (float)((m & 15) + 1);
        }
    } else if (blk < 772) {
        // ---------- strided residue class mod 65: rows l = r + 65*s, s=0..31
        int us = (blk - 512) * 4 + wib;  // 0..1039
        int bh = us / SP_;
        int r  = us % SP_;
        int h = bh & 7, b = bh >> 3;
        const size_t base = (size_t)b * L_ * RS_ + (size_t)h * D_;
        float* Pw = LDS + wib * 1152;    // [32][36]

        bf16x8 bv0[2], bv1[2];
        #pragma unroll
        for (int kb = 0; kb < 2; ++kb) {
            int k0 = kb * 16 + half * 8;
            #pragma unroll
            for (int jj = 0; jj < 8; ++jj) {
                int lv = r + SP_ * (k0 + jj);
                lv = lv > L_ - 1 ? L_ - 1 : lv;
                const float* vr = v + base + (size_t)lv * RS_;
                bv0[kb][jj] = f2bf(vr[ln]);
                bv1[kb][jj] = f2bf(vr[32 + ln]);
            }
        }

        int lq = r + SP_ * ln;
        int lqc = lq > L_ - 1 ? L_ - 1 : lq;
        const float* qrow = q  + base + (size_t)lqc * RS_;
        const float* krow = kk + base + (size_t)lqc * RS_;
        f32x16 acc = {};
        #pragma unroll
        for (int kb = 0; kb < 4; ++kb) {
            bf16x8 a  = ld8_bf16(qrow + kb * 16 + half * 8);
            bf16x8 bb = ld8_bf16(krow + kb * 16 + half * 8);
            acc = __builtin_amdgcn_mfma_f32_32x32x16_bf16(a, bb, acc, 0, 0, 0);
        }
        #pragma unroll
        for (int rg = 0; rg < 16; ++rg) {
            int m = (rg & 3) + 8 * (rg >> 2) + 4 * half;
            bool act = (ln < m) && (r + SP_ * m < L_);
            Pw[m * 36 + ln] = act ? (__expf(0.125f * acc[rg]) - 1.f) : 0.f;
        }
        __syncthreads();

        f32x16 p0 = {}; f32x16 p1 = {}; f32x16 po = {};
        bf16x8 ones = ones_frag();
        #pragma unroll
        for (int kb = 0; kb < 2; ++kb) {
            int k0 = kb * 16 + half * 8;
            const float* pr = &Pw[ln * 36 + k0];
            float4 x = *(const float4*)pr;
            float4 y = *(const float4*)(pr + 4);
            bf16x8 ap;
            ap[0]=f2bf(x.x); ap[1]=f2bf(x.y); ap[2]=f2bf(x.z); ap[3]=f2bf(x.w);
            ap[4]=f2bf(y.x); ap[5]=f2bf(y.y); ap[6]=f2bf(y.z); ap[7]=f2bf(y.w);
            p0 = __builtin_amdgcn_mfma_f32_32x32x16_bf16(ap, bv0[kb], p0, 0, 0, 0);
            p1 = __builtin_amdgcn_mfma_f32_32x32x16_bf16(ap, bv1[kb], p1, 0, 0, 0);
            po = __builtin_amdgcn_mfma_f32_32x32x16_bf16(ap, ones,    po, 0, 0, 0);
        }
        float* pBr = pB + (size_t)bh * L_ * D_;
        float* zBr = zB + (size_t)bh * L_;
        #pragma unroll
        for (int rg = 0; rg < 16; ++rg) {
            int m = (rg & 3) + 8 * (rg >> 2) + 4 * half;
            int l = r + SP_ * m;
            if (l < L_) {
                pBr[(size_t)l * D_ + ln]      = p0[rg];
                pBr[(size_t)l * D_ + 32 + ln] = p1[rg];
                if (ln == 0) zBr[l] = po[rg];
            }
        }
    } else {
        // ---------- csum1: 16-row chunk sums of V
        int uc = (blk - 772) * 4 + wib;  // 0..2047 = bh*128 + c
        int c = uc & (NC_ - 1);
        int bh = uc >> 7;
        int h = bh & 7, b = bh >> 3;
        const float* vb = v + (size_t)(b * L_ + c * 16) * RS_ + h * D_ + lane;
        float s = 0.f;
        #pragma unroll
        for (int l = 0; l < 16; ++l) s += vb[l * RS_];
        csum1[(size_t)uc * D_ + lane] = s;
    }
}

// ================= Kernel 2: combine + prefix + divide (streaming) ==========
// One wave per 8-row group (4096 waves, 1024 blocks). Lane = dim.
__global__ __launch_bounds__(256) void combine_k(const float* __restrict__ csum1,
                                                 const float* __restrict__ pA,
                                                 const float* __restrict__ zA,
                                                 const float* __restrict__ pB,
                                                 const float* __restrict__ zB,
                                                 float* __restrict__ out) {
    int wib  = threadIdx.x >> 6;
    int lane = threadIdx.x & 63;
    int u = blockIdx.x * 4 + wib;        // 0..4095
    int bh = u >> 8;
    int g  = u & 255;                    // 8-row group
    int i0 = g << 3;
    int c1 = i0 >> 4;                    // full 16-row chunks below this group
    int h = bh & 7, b = bh >> 3;

    // prefix walk over csum1 (L2-hot, independent loads, 4-way unrolled)
    const float* cs1 = csum1 + (size_t)bh * NC_ * D_ + lane;
    float s0 = 0.f, s1 = 0.f, s2 = 0.f, s3 = 0.f;
    int cc = 0;
    for (; cc + 4 <= c1; cc += 4) {
        s0 += cs1[(cc + 0) * D_]; s1 += cs1[(cc + 1) * D_];
        s2 += cs1[(cc + 2) * D_]; s3 += cs1[(cc + 3) * D_];
    }
    for (; cc < c1; ++cc) s0 += cs1[cc * D_];
    float pr = (s0 + s1) + (s2 + s3);

    const float* pAr = pA + (size_t)bh * L_ * D_;
    const float* pBr = pB + (size_t)bh * L_ * D_;
    const float* zAr = zA + (size_t)bh * L_;
    const float* zBr = zB + (size_t)bh * L_;
    const size_t obase = (size_t)b * L_ * RS_ + (size_t)h * D_;

    #pragma unroll
    for (int r = 0; r < 8; ++r) {
        int i = i0 + r;
        float num = pAr[(size_t)i * D_ + lane] + pBr[(size_t)i * D_ + lane] + pr;
        float inv = 1.f / (zAr[i] + zBr[i] + (float)(i + 1));
        out[obase + (size_t)i * RS_ + lane] = num * inv;
    }
}

extern "C" void kernel_launch(void* const* d_in, const int* in_sizes, int n_in,
                              void* d_out, int out_size, void* d_ws, size_t ws_size,
                              hipStream_t stream) {
    const float* q = (const float*)d_in[0];
    const float* k = (const float*)d_in[1];
    const float* v = (const float*)d_in[2];
    // d_in[3] = attn_mask: deterministic causal — not read.
    float* out = (float*)d_out;

    float* csum1 = (float*)d_ws;                          // 131072 f
    float* pA    = csum1 + (size_t)B_ * H_ * NC_ * D_;    // 2097152 f
    float* zA    = pA    + (size_t)B_ * H_ * L_ * D_;     // 32768 f
    float* pB    = zA    + (size_t)B_ * H_ * L_;          // 2097152 f
    float* zB    = pB    + (size_t)B_ * H_ * L_ * D_;     // 32768 f

    // 512 local-team + 260 strided + 512 csum1 blocks
    partials_k<<<1284, 256, 0, stream>>>(q, k, v, csum1, pA, zA, pB, zB);
    // combine: 4096 8-row groups, 4 waves/block
    combine_k<<<1024, 256, 0, stream>>>(csum1, pA, zA, pB, zB, out);
}